// Round 16
// baseline (186.151 us; speedup 1.0000x reference)
//
#include <hip/hip_runtime.h>
#include <math.h>

typedef __bf16 bf16_t;
typedef __attribute__((ext_vector_type(8))) __bf16 bf16x8;
typedef __attribute__((ext_vector_type(4))) float f32x4;

#define B_  4
#define T_  2048
#define D_  1024
#define H_  16
#define HD_ 64
#define D3_ 3072

__device__ __forceinline__ void load_lds16(const bf16_t* g, char* lds) {
  __builtin_amdgcn_global_load_lds(
      (const __attribute__((address_space(1))) void*)g,
      (__attribute__((address_space(3))) void*)lds, 16, 0, 0);
}

// ---------------------------------------------------------------------------
// fp32 -> bf16 elementwise convert (vectorized)
// ---------------------------------------------------------------------------
__global__ __launch_bounds__(256) void convert_bf16(
    const float* __restrict__ in, bf16_t* __restrict__ out, int n4) {
  int idx = blockIdx.x * 256 + threadIdx.x;
  int stride = gridDim.x * 256;
  for (int i = idx; i < n4; i += stride) {
    float4 v = ((const float4*)in)[i];
    alignas(8) bf16_t o4[4] = {(bf16_t)v.x, (bf16_t)v.y, (bf16_t)v.z, (bf16_t)v.w};
    ((uint2*)out)[i] = *(const uint2*)o4;
  }
}

// ---------------------------------------------------------------------------
// Both weights (K x N fp32) -> (N x K bf16) in ONE launch.
// ---------------------------------------------------------------------------
__global__ __launch_bounds__(256) void transpose_convert2(
    const float* __restrict__ Wa, bf16_t* __restrict__ Wat,
    const float* __restrict__ Wp, bf16_t* __restrict__ Wpt) {
  __shared__ float tile[64][65];
  int by = blockIdx.y;
  const float* W;
  bf16_t* Wt;
  int N;
  if (by < 48) {
    W = Wa; Wt = Wat; N = D3_;
  } else {
    W = Wp; Wt = Wpt; N = D_; by -= 48;
  }
  const int K = D_;
  const int k0 = blockIdx.x * 64, n0 = by * 64;
  const int tid = threadIdx.x;
  const int r = tid >> 4, c4 = (tid & 15) * 4;
#pragma unroll
  for (int i = 0; i < 4; ++i) {
    float4 v = *(const float4*)(W + (size_t)(k0 + r + i * 16) * N + n0 + c4);
    tile[r + i * 16][c4 + 0] = v.x;
    tile[r + i * 16][c4 + 1] = v.y;
    tile[r + i * 16][c4 + 2] = v.z;
    tile[r + i * 16][c4 + 3] = v.w;
  }
  __syncthreads();
#pragma unroll
  for (int i = 0; i < 4; ++i) {
    int n = r + i * 16;
    alignas(8) bf16_t o4[4];
#pragma unroll
    for (int j = 0; j < 4; ++j) o4[j] = (bf16_t)tile[c4 + j][n];
    *(uint2*)(Wt + (size_t)(n0 + n) * K + k0 + c4) = *(const uint2*)o4;
  }
}

// ---------------------------------------------------------------------------
// R16: fine-grained 8-phase GEMM (QKV only). 256x128 tile, BK=64 as 2
// k-halves of 32; 8 waves (4M x 2N, 64x64 each); 2 phases per K-tile,
// 16 MFMA per phase. LDS 96 KB: A[2dbuf][2kh][256x32], B[2][2][128x32],
// each k-half contiguous (linear global_load_lds dest) + chunk-XOR swizzle.
// Schedule per phase: {8 ds_read_b128 ; stage 1 half-tile-pair (3 loads:
// 2A+1B) ; s_barrier ; 16 MFMA (setprio) ; vmcnt(6) ; s_barrier}.
// Ledger (verified by issue order): prologue stages (0)k0,(0)k1,(1)k0
// (9 loads) + vmcnt(6)+barrier -> (0)k0 landed. phA(t) stages (t+1)k1,
// phB(t) stages (t+2)k0; vmcnt(6) before each end-barrier lands exactly
// the next phase's data for ALL waves (barrier makes it block-wide).
// WAR: dest region's readers sampled (lgkmcnt before MFMA) before the
// end-barrier that precedes the overwriting stage's issue. Tail: source
// tile clamped, dest dbuf follows the UNCLAMPED schedule (dead regions).
// ---------------------------------------------------------------------------
#define PBM 256
#define PBN 128
#define PBK 64

__global__ __launch_bounds__(512, 1) void gemm_bt_8ph(
    const bf16_t* __restrict__ A, const bf16_t* __restrict__ Bt,
    const float* __restrict__ bias, bf16_t* __restrict__ C,
    int M, int N, int K) {
  __shared__ __align__(16) bf16_t Ash[2][2][PBM * 32];  // 64 KB
  __shared__ __align__(16) bf16_t Bsh[2][2][PBN * 32];  // 32 KB

  const int tid = threadIdx.x;
  const int l = tid & 63, w = tid >> 6;
  const int l15 = l & 15, lhi = l >> 4;
  const int wm = w >> 1, wn = w & 1;  // 4M x 2N waves

  // XCD-aware bijective remap (gridDim.x % 8 == 0)
  const int nbx = N / PBN;
  const int cpx = gridDim.x >> 3;
  const int swz = (blockIdx.x & 7) * cpx + (blockIdx.x >> 3);
  const int row0 = (swz / nbx) * PBM, col0 = (swz % nbx) * PBN;

  const bf16_t* Abase = A + (size_t)row0 * K;
  const bf16_t* Bbase = Bt + (size_t)col0 * K;

  // staging lane map: phys chunk = tid&3 at row R -> logical = (tid&3)^(R&3)
  const int sR = tid >> 2;                // 0..127
  const int sLc = (tid & 3) ^ (sR & 3);
  // fragment read: logical chunk lhi at row (..+l15) -> phys = lhi^(l15&3)
  const int rc = (lhi ^ (l15 & 3)) * 8;

  auto stageA = [&](int tdst, int tsrc, int kh) {
    const int k0 = tsrc * PBK + kh * 32;
#pragma unroll
    for (int i2 = 0; i2 < 2; ++i2) {
      int R = i2 * 128 + sR;  // R&3 == sR&3
      load_lds16(Abase + (size_t)R * K + k0 + sLc * 8,
                 (char*)&Ash[tdst & 1][kh][0] + i2 * 8192 + tid * 16);
    }
  };
  auto stageB = [&](int tdst, int tsrc, int kh) {
    const int k0 = tsrc * PBK + kh * 32;
    load_lds16(Bbase + (size_t)sR * K + k0 + sLc * 8,
               (char*)&Bsh[tdst & 1][kh][0] + tid * 16);
  };

  f32x4 acc[4][4];
#pragma unroll
  for (int i = 0; i < 4; ++i)
#pragma unroll
    for (int j = 0; j < 4; ++j) acc[i][j] = (f32x4){0.f, 0.f, 0.f, 0.f};

  const int nt = K / PBK;  // 16

  // prologue: (0).k0, (0).k1, (1).k0  (A then B each; 9 loads)
  stageA(0, 0, 0); stageB(0, 0, 0);
  stageA(0, 0, 1); stageB(0, 0, 1);
  stageA(1, 1, 0); stageB(1, 1, 0);
  asm volatile("s_waitcnt vmcnt(6)" ::: "memory");  // (0).k0 landed
  __builtin_amdgcn_s_barrier();
  asm volatile("" ::: "memory");

  for (int t = 0; t < nt; ++t) {
    const int d = t & 1;
    // ---------- phase A: k-half 0 ----------
    {
      bf16x8 af[4], bfj[4];
#pragma unroll
      for (int i = 0; i < 4; ++i)
        af[i] = *(const bf16x8*)&Ash[d][0][(wm * 64 + i * 16 + l15) * 32 + rc];
#pragma unroll
      for (int j = 0; j < 4; ++j)
        bfj[j] = *(const bf16x8*)&Bsh[d][0][(wn * 64 + j * 16 + l15) * 32 + rc];
      const int t1 = t + 1, t1c = (t1 < nt) ? t1 : nt - 1;
      stageA(t1, t1c, 1);
      stageB(t1, t1c, 1);
      __builtin_amdgcn_s_barrier();
      asm volatile("" ::: "memory");
      __builtin_amdgcn_s_setprio(1);
#pragma unroll
      for (int i = 0; i < 4; ++i)
#pragma unroll
        for (int j = 0; j < 4; ++j)
          acc[i][j] =
              __builtin_amdgcn_mfma_f32_16x16x32_bf16(af[i], bfj[j], acc[i][j], 0, 0, 0);
      __builtin_amdgcn_s_setprio(0);
      asm volatile("s_waitcnt vmcnt(6)" ::: "memory");  // (t).k1 landed
      __builtin_amdgcn_s_barrier();
      asm volatile("" ::: "memory");
    }
    // ---------- phase B: k-half 1 ----------
    {
      bf16x8 af[4], bfj[4];
#pragma unroll
      for (int i = 0; i < 4; ++i)
        af[i] = *(const bf16x8*)&Ash[d][1][(wm * 64 + i * 16 + l15) * 32 + rc];
#pragma unroll
      for (int j = 0; j < 4; ++j)
        bfj[j] = *(const bf16x8*)&Bsh[d][1][(wn * 64 + j * 16 + l15) * 32 + rc];
      const int t2 = t + 2, t2c = (t2 < nt) ? t2 : nt - 1;
      stageA(t2, t2c, 0);
      stageB(t2, t2c, 0);
      __builtin_amdgcn_s_barrier();
      asm volatile("" ::: "memory");
      __builtin_amdgcn_s_setprio(1);
#pragma unroll
      for (int i = 0; i < 4; ++i)
#pragma unroll
        for (int j = 0; j < 4; ++j)
          acc[i][j] =
              __builtin_amdgcn_mfma_f32_16x16x32_bf16(af[i], bfj[j], acc[i][j], 0, 0, 0);
      __builtin_amdgcn_s_setprio(0);
      asm volatile("s_waitcnt vmcnt(6)" ::: "memory");  // (t+1).k0 landed
      __builtin_amdgcn_s_barrier();
      asm volatile("" ::: "memory");
    }
  }

  // epilogue: C/D layout col=l&15, row=(l>>4)*4+reg
#pragma unroll
  for (int j = 0; j < 4; ++j) {
    int colr = col0 + wn * 64 + j * 16 + l15;
    float bv = bias[colr];
#pragma unroll
    for (int i = 0; i < 4; ++i) {
#pragma unroll
      for (int r = 0; r < 4; ++r) {
        int rowr = row0 + wm * 64 + i * 16 + lhi * 4 + r;
        C[(size_t)rowr * N + colr] = (bf16_t)(acc[i][j][r] + bv);
      }
    }
  }
}

// ---------------------------------------------------------------------------
// bf16 MFMA GEMM (128x128, 2-phase dbuf, XCD swizzle) — proj GEMM.
// ---------------------------------------------------------------------------
#define GBM 128
#define GBN 128
#define GBK 32

template <bool BF16_OUT>
__global__ __launch_bounds__(256) void gemm_bt_mfma(
    const bf16_t* __restrict__ A, const bf16_t* __restrict__ Bt,
    const float* __restrict__ bias, void* __restrict__ Cv,
    int M, int N, int K) {
  __shared__ __align__(16) bf16_t Asl[2][GBM * GBK];
  __shared__ __align__(16) bf16_t Bsl[2][GBN * GBK];

  const int tid = threadIdx.x;
  const int w = tid >> 6, l = tid & 63;
  const int l15 = l & 15, lhi = l >> 4;

  const int nbx = N / GBN;
  const int cpx = gridDim.x >> 3;
  const int swz = (blockIdx.x & 7) * cpx + (blockIdx.x >> 3);
  const int row0 = (swz / nbx) * GBM, col0 = (swz % nbx) * GBN;
  const int wr = (w >> 1) * 64, wc = (w & 1) * 64;

  const int srow = tid >> 2;
  const int sf = (srow & 3) ^ ((srow >> 2) & 3);
  const int slog = (tid & 3) ^ sf;
  const int rf = (l15 & 3) ^ ((l15 >> 2) & 3);
  const int rchunk = lhi ^ rf;

  f32x4 acc[4][4];
#pragma unroll
  for (int i = 0; i < 4; ++i)
#pragma unroll
    for (int j = 0; j < 4; ++j) acc[i][j] = (f32x4){0.f, 0.f, 0.f, 0.f};

  const bf16_t* Abase = A + (size_t)row0 * K;
  const bf16_t* Bbase = Bt + (size_t)col0 * K;

  auto stage = [&](int buf, int k0) {
#pragma unroll
    for (int issue = 0; issue < 2; ++issue) {
      const bf16_t* ga = Abase + (size_t)(issue * 64 + srow) * K + k0 + slog * 8;
      load_lds16(ga, (char*)&Asl[buf][0] + issue * 4096 + w * 1024);
      const bf16_t* gb = Bbase + (size_t)(issue * 64 + srow) * K + k0 + slog * 8;
      load_lds16(gb, (char*)&Bsl[buf][0] + issue * 4096 + w * 1024);
    }
  };

  const int nt = K / GBK;
  stage(0, 0);

  for (int t = 0; t < nt; ++t) {
    __syncthreads();
    if (t + 1 < nt) stage((t + 1) & 1, (t + 1) * GBK);

    const bf16_t* As = &Asl[t & 1][0];
    const bf16_t* Bs = &Bsl[t & 1][0];
    bf16x8 af[4], bf[4];
#pragma unroll
    for (int i = 0; i < 4; ++i)
      af[i] = *(const bf16x8*)&As[(wr + i * 16 + l15) * GBK + rchunk * 8];
#pragma unroll
    for (int j = 0; j < 4; ++j)
      bf[j] = *(const bf16x8*)&Bs[(wc + j * 16 + l15) * GBK + rchunk * 8];
#pragma unroll
    for (int i = 0; i < 4; ++i)
#pragma unroll
      for (int j = 0; j < 4; ++j)
        acc[i][j] =
            __builtin_amdgcn_mfma_f32_16x16x32_bf16(af[i], bf[j], acc[i][j], 0, 0, 0);
  }

#pragma unroll
  for (int j = 0; j < 4; ++j) {
    int colr = col0 + wc + j * 16 + l15;
    float bv = bias[colr];
#pragma unroll
    for (int i = 0; i < 4; ++i) {
#pragma unroll
      for (int r = 0; r < 4; ++r) {
        int rowr = row0 + wr + i * 16 + lhi * 4 + r;
        float val = acc[i][j][r] + bv;
        if constexpr (BF16_OUT)
          ((bf16_t*)Cv)[(size_t)rowr * N + colr] = (bf16_t)val;
        else
          ((float*)Cv)[(size_t)rowr * N + colr] = val;
      }
    }
  }
}

// ---------------------------------------------------------------------------
// Transpose V out of qkv_bf into Vg[bh][d][t] (bf16).
// ---------------------------------------------------------------------------
__global__ __launch_bounds__(256) void transpose_v(
    const bf16_t* __restrict__ qkv, bf16_t* __restrict__ Vg) {
  const int bh = blockIdx.y;
  const int b = bh >> 4, h = bh & 15;
  const int t0 = blockIdx.x * 64;
  const int tid = threadIdx.x;
  const int d = tid & 63;
  const int w = tid >> 6;
  alignas(16) bf16_t tmp[16];
#pragma unroll
  for (int j = 0; j < 16; ++j) {
    int t = t0 + w * 16 + j;
    tmp[j] = qkv[(size_t)(b * T_ + t) * D3_ + 2 * D_ + h * HD_ + d];
  }
  bf16_t* dst = Vg + (size_t)(bh * HD_ + d) * T_ + t0 + w * 16;
  *(uint4*)(dst) = *(const uint4*)(tmp);
  *(uint4*)(dst + 8) = *(const uint4*)(tmp + 8);
}

// ---------------------------------------------------------------------------
// Causal flash attention (R12 form, unchanged): swapped-QK^T 16x16x32 MFMA,
// 4 waves / QBLK=128, 2-barrier staged loop, fixed-max softmax (c=8).
// ---------------------------------------------------------------------------
#define QBLK 128
#define KBLK 64

__global__ __launch_bounds__(256, 4) void attn_fwd_mfma(
    const bf16_t* __restrict__ qkv, const bf16_t* __restrict__ Vg,
    bf16_t* __restrict__ y) {
  const int lin = blockIdx.x;
  const int bh = (lin & 7) * 8 + ((lin >> 3) & 7);  // XCD-local heads
  const int qt = (T_ / QBLK - 1) - (lin >> 6);      // tail-first
  const int b = bh >> 4, h = bh & 15;
  const int Q0 = qt * QBLK;
  const int tid = threadIdx.x;
  const int w = tid >> 6, l = tid & 63;
  const int l15 = l & 15, lhi = l >> 4;

  __shared__ __align__(16) bf16_t K_lds[2][KBLK * 64];
  __shared__ __align__(16) bf16_t V_lds[KBLK * 64];
  __shared__ __align__(16) bf16_t P_lds[4][16][72];

  const int sr = tid >> 3, sp = tid & 7;
  const int slc = sp ^ (sr & 7);
  const int swz = (l15 & 7);

  auto stageK = [&](int buf, int kt) {
    const bf16_t* src =
        qkv + (size_t)(b * T_ + kt * KBLK + sr) * D3_ + D_ + h * HD_ + slc * 8;
    char* dst = (char*)(&K_lds[buf][0]) + w * 1024;
    load_lds16(src, dst);
    load_lds16(src + (size_t)32 * D3_, dst + 4096);
  };
  auto stageV = [&](int kt) {
    const bf16_t* src = Vg + ((size_t)bh * HD_ + sr) * T_ + kt * KBLK + slc * 8;
    char* dst = (char*)(&V_lds[0]) + w * 1024;
    load_lds16(src, dst);
    load_lds16(src + (size_t)32 * T_, dst + 4096);
  };

  bf16x8 qf[2][2];
#pragma unroll
  for (int g = 0; g < 2; ++g) {
    int q = Q0 + w * 32 + g * 16 + l15;
#pragma unroll
    for (int c = 0; c < 2; ++c) {
      const bf16_t* p = qkv + (size_t)(b * T_ + q) * D3_ + h * HD_ + c * 32 + lhi * 8;
      bf16x8 v = *(const bf16x8*)p;
#pragma unroll
      for (int e = 0; e < 8; ++e) v[e] = (bf16_t)((float)v[e] * 0.125f);
      qf[g][c] = v;
    }
  }

  f32x4 accO[2][4];
#pragma unroll
  for (int g = 0; g < 2; ++g)
#pragma unroll
    for (int dg = 0; dg < 4; ++dg) accO[g][dg] = (f32x4){0.f, 0.f, 0.f, 0.f};
  float lsum[2] = {0.f, 0.f};
  const float FMAX = 8.f;

  const int ntiles = Q0 / KBLK + 2;
  const int qg0 = Q0 + w * 32;
  const int qg1 = qg0 + 16;

  stageK(0, 0);
  __syncthreads();

  for (int kt = 0; kt < ntiles; ++kt) {
    const int cur = kt & 1;
    const int ktb = kt * KBLK;
    stageV(kt);
    if (kt + 1 < ntiles) stageK(cur ^ 1, kt + 1);

    const bool act0 = (ktb <= qg0 + 15);
    const bool act1 = (ktb <= qg1 + 15);
    uint2 pp1[4];

#pragma unroll
    for (int g = 0; g < 2; ++g) {
      if (!(g == 0 ? act0 : act1)) continue;
      const int qg = g == 0 ? qg0 : qg1;

      f32x4 s[4];
#pragma unroll
      for (int n = 0; n < 4; ++n) s[n] = (f32x4){0.f, 0.f, 0.f, 0.f};
      __builtin_amdgcn_s_setprio(1);
#pragma unroll
      for (int c = 0; c < 2; ++c) {
#pragma unroll
        for (int n = 0; n < 4; ++n) {
          bf16x8 kf = *(const bf16x8*)&K_lds[cur][(n * 16 + l15) * 64 +
                                                 (((c * 4 + lhi) ^ swz) * 8)];
          s[n] = __builtin_amdgcn_mfma_f32_16x16x32_bf16(kf, qf[g][c], s[n], 0, 0, 0);
        }
      }
      __builtin_amdgcn_s_setprio(0);

      if (ktb + KBLK - 1 > qg) {
        const int qml = qg + l15 - ktb - lhi * 4;
#pragma unroll
        for (int n = 0; n < 4; ++n)
#pragma unroll
          for (int r = 0; r < 4; ++r)
            if (n * 16 + r > qml) s[n][r] = -INFINITY;
      }

      float rowsum = 0.f;
#pragma unroll
      for (int n = 0; n < 4; ++n) {
        alignas(8) bf16_t p4[4];
#pragma unroll
        for (int r = 0; r < 4; ++r) {
          float p = __expf(s[n][r] - FMAX);
          rowsum += p;
          p4[r] = (bf16_t)p;
        }
        if (g == 0)
          *(uint2*)&P_lds[w][l15][n * 16 + lhi * 4] = *(const uint2*)p4;
        else
          pp1[n] = *(const uint2*)p4;
      }
      lsum[g] += rowsum;
    }

    __syncthreads();

    if (act0) {
      __builtin_amdgcn_s_setprio(1);
#pragma unroll
      for (int c2 = 0; c2 < 2; ++c2) {
        bf16x8 pf = *(const bf16x8*)&P_lds[w][l15][c2 * 32 + lhi * 8];
#pragma unroll
        for (int dg = 0; dg < 4; ++dg) {
          bf16x8 vf = *(const bf16x8*)&V_lds[(dg * 16 + l15) * 64 +
                                             (((c2 * 4 + lhi) ^ swz) * 8)];
          accO[0][dg] =
              __builtin_amdgcn_mfma_f32_16x16x32_bf16(pf, vf, accO[0][dg], 0, 0, 0);
        }
      }
      __builtin_amdgcn_s_setprio(0);
    }
    if (act1) {
#pragma unroll
      for (int n = 0; n < 4; ++n)
        *(uint2*)&P_lds[w][l15][n * 16 + lhi * 4] = pp1[n];
      __builtin_amdgcn_s_setprio(1);
#pragma unroll
      for (int c2 = 0; c2 < 2; ++c2) {
        bf16x8 pf = *(const bf16x8*)&P_lds[w][l15][c2 * 32 + lhi * 8];
#pragma unroll
        for (int dg = 0; dg < 4; ++dg) {
          bf16x8 vf = *(const bf16x8*)&V_lds[(dg * 16 + l15) * 64 +
                                             (((c2 * 4 + lhi) ^ swz) * 8)];
          accO[1][dg] =
              __builtin_amdgcn_mfma_f32_16x16x32_bf16(pf, vf, accO[1][dg], 0, 0, 0);
        }
      }
      __builtin_amdgcn_s_setprio(0);
    }

    __syncthreads();
  }

#pragma unroll
  for (int g = 0; g < 2; ++g) {
    float ls = lsum[g];
    ls += __shfl_xor(ls, 16);
    ls += __shfl_xor(ls, 32);
#pragma unroll
    for (int r = 0; r < 4; ++r) {
      float lr = __shfl(ls, lhi * 4 + r);
      float inv = 1.f / lr;
      int q = Q0 + w * 32 + g * 16 + lhi * 4 + r;
      bf16_t* yr = y + (size_t)(b * T_ + q) * D_ + h * HD_ + l15;
#pragma unroll
      for (int dg = 0; dg < 4; ++dg) yr[dg * 16] = (bf16_t)(accO[g][dg][r] * inv);
    }
  }
}

// ---------------------------------------------------------------------------
extern "C" void kernel_launch(void* const* d_in, const int* in_sizes, int n_in,
                              void* d_out, int out_size, void* d_ws, size_t ws_size,
                              hipStream_t stream) {
  const float* x      = (const float*)d_in[0];
  const float* w_attn = (const float*)d_in[1];
  const float* b_attn = (const float*)d_in[2];
  const float* w_proj = (const float*)d_in[3];
  const float* b_proj = (const float*)d_in[4];
  float* out = (float*)d_out;

  const int M = B_ * T_;  // 8192

  bf16_t* xb      = (bf16_t*)d_ws;                         // 16 MB (reused as y_bf)
  bf16_t* wattnT  = xb + (size_t)M * D_;                   // 6 MB
  bf16_t* wprojT  = wattnT + (size_t)D3_ * D_;             // 2 MB
  bf16_t* qkv_bf  = wprojT + (size_t)D_ * D_;              // 48 MB
  bf16_t* Vg      = qkv_bf + (size_t)M * D3_;              // 16 MB
  bf16_t* y_bf    = xb;

  convert_bf16<<<2048, 256, 0, stream>>>(x, xb, M * D_ / 4);
  transpose_convert2<<<dim3(D_ / 64, 64), 256, 0, stream>>>(
      w_attn, wattnT, w_proj, wprojT);
  // QKV GEMM: fine-grained 8-phase 256x128 kernel (768 blocks = 3/CU)
  gemm_bt_8ph<<<(M / PBM) * (D3_ / PBN), 512, 0, stream>>>(
      xb, wattnT, b_attn, qkv_bf, M, D3_, D_);
  transpose_v<<<dim3(T_ / 64, B_ * H_), 256, 0, stream>>>(qkv_bf, Vg);
  attn_fwd_mfma<<<dim3(T_ / QBLK * B_ * H_), 256, 0, stream>>>(qkv_bf, Vg, y_bf);
  // proj GEMM: proven 128^2 kernel (512 blocks, XCD-swizzled)
  gemm_bt_mfma<false><<<(D_ / GBN) * (M / GBM), 256, 0, stream>>>(
      y_bf, wprojT, b_proj, out, M, D_, D_);
}

// Round 17
// 177.658 us; speedup vs baseline: 1.0478x; 1.0478x over previous
//
#include <hip/hip_runtime.h>
#include <math.h>

typedef __bf16 bf16_t;
typedef __attribute__((ext_vector_type(8))) __bf16 bf16x8;
typedef __attribute__((ext_vector_type(4))) float f32x4;

#define B_  4
#define T_  2048
#define D_  1024
#define H_  16
#define HD_ 64
#define D3_ 3072

__device__ __forceinline__ void load_lds16(const bf16_t* g, char* lds) {
  __builtin_amdgcn_global_load_lds(
      (const __attribute__((address_space(1))) void*)g,
      (__attribute__((address_space(3))) void*)lds, 16, 0, 0);
}

// ---------------------------------------------------------------------------
// fp32 -> bf16 elementwise convert (vectorized)
// ---------------------------------------------------------------------------
__global__ __launch_bounds__(256) void convert_bf16(
    const float* __restrict__ in, bf16_t* __restrict__ out, int n4) {
  int idx = blockIdx.x * 256 + threadIdx.x;
  int stride = gridDim.x * 256;
  for (int i = idx; i < n4; i += stride) {
    float4 v = ((const float4*)in)[i];
    alignas(8) bf16_t o4[4] = {(bf16_t)v.x, (bf16_t)v.y, (bf16_t)v.z, (bf16_t)v.w};
    ((uint2*)out)[i] = *(const uint2*)o4;
  }
}

// ---------------------------------------------------------------------------
// Both weights (K x N fp32) -> (N x K bf16) in ONE launch.
// by < 48: w_attn (N=3072); else w_proj (N=1024). K=1024 for both.
// ---------------------------------------------------------------------------
__global__ __launch_bounds__(256) void transpose_convert2(
    const float* __restrict__ Wa, bf16_t* __restrict__ Wat,
    const float* __restrict__ Wp, bf16_t* __restrict__ Wpt) {
  __shared__ float tile[64][65];
  int by = blockIdx.y;
  const float* W;
  bf16_t* Wt;
  int N;
  if (by < 48) {
    W = Wa; Wt = Wat; N = D3_;
  } else {
    W = Wp; Wt = Wpt; N = D_; by -= 48;
  }
  const int K = D_;
  const int k0 = blockIdx.x * 64, n0 = by * 64;
  const int tid = threadIdx.x;
  const int r = tid >> 4, c4 = (tid & 15) * 4;
#pragma unroll
  for (int i = 0; i < 4; ++i) {
    float4 v = *(const float4*)(W + (size_t)(k0 + r + i * 16) * N + n0 + c4);
    tile[r + i * 16][c4 + 0] = v.x;
    tile[r + i * 16][c4 + 1] = v.y;
    tile[r + i * 16][c4 + 2] = v.z;
    tile[r + i * 16][c4 + 3] = v.w;
  }
  __syncthreads();
#pragma unroll
  for (int i = 0; i < 4; ++i) {
    int n = r + i * 16;
    alignas(8) bf16_t o4[4];
#pragma unroll
    for (int j = 0; j < 4; ++j) o4[j] = (bf16_t)tile[c4 + j][n];
    *(uint2*)(Wt + (size_t)(n0 + n) * K + k0 + c4) = *(const uint2*)o4;
  }
}

// ---------------------------------------------------------------------------
// bf16 MFMA GEMM (128x128, 2-phase dbuf) — proven structure (R5/R12).
// R15: 1D grid + bijective XCD swizzle (T1; grid % 8 == 0 for both calls):
// block orig lands on XCD orig%8 and computes tile swz=(orig%8)*cpx+orig/8,
// so each XCD owns a contiguous slab of block-rows (B-panel L2 reuse).
// ---------------------------------------------------------------------------
#define GBM 128
#define GBN 128
#define GBK 32

template <bool BF16_OUT>
__global__ __launch_bounds__(256) void gemm_bt_mfma(
    const bf16_t* __restrict__ A, const bf16_t* __restrict__ Bt,
    const float* __restrict__ bias, void* __restrict__ Cv,
    int M, int N, int K) {
  __shared__ __align__(16) bf16_t Asl[2][GBM * GBK];
  __shared__ __align__(16) bf16_t Bsl[2][GBN * GBK];

  const int tid = threadIdx.x;
  const int w = tid >> 6, l = tid & 63;
  const int l15 = l & 15, lhi = l >> 4;

  // XCD-aware bijective remap (gridDim.x % 8 == 0)
  const int nbx = N / GBN;
  const int cpx = gridDim.x >> 3;
  const int swz = (blockIdx.x & 7) * cpx + (blockIdx.x >> 3);
  const int row0 = (swz / nbx) * GBM, col0 = (swz % nbx) * GBN;
  const int wr = (w >> 1) * 64, wc = (w & 1) * 64;

  const int srow = tid >> 2;
  const int sf = (srow & 3) ^ ((srow >> 2) & 3);
  const int slog = (tid & 3) ^ sf;
  const int rf = (l15 & 3) ^ ((l15 >> 2) & 3);
  const int rchunk = lhi ^ rf;

  f32x4 acc[4][4];
#pragma unroll
  for (int i = 0; i < 4; ++i)
#pragma unroll
    for (int j = 0; j < 4; ++j) acc[i][j] = (f32x4){0.f, 0.f, 0.f, 0.f};

  const bf16_t* Abase = A + (size_t)row0 * K;
  const bf16_t* Bbase = Bt + (size_t)col0 * K;

  auto stage = [&](int buf, int k0) {
#pragma unroll
    for (int issue = 0; issue < 2; ++issue) {
      const bf16_t* ga = Abase + (size_t)(issue * 64 + srow) * K + k0 + slog * 8;
      load_lds16(ga, (char*)&Asl[buf][0] + issue * 4096 + w * 1024);
      const bf16_t* gb = Bbase + (size_t)(issue * 64 + srow) * K + k0 + slog * 8;
      load_lds16(gb, (char*)&Bsl[buf][0] + issue * 4096 + w * 1024);
    }
  };

  const int nt = K / GBK;
  stage(0, 0);

  for (int t = 0; t < nt; ++t) {
    __syncthreads();
    if (t + 1 < nt) stage((t + 1) & 1, (t + 1) * GBK);

    const bf16_t* As = &Asl[t & 1][0];
    const bf16_t* Bs = &Bsl[t & 1][0];
    bf16x8 af[4], bf[4];
#pragma unroll
    for (int i = 0; i < 4; ++i)
      af[i] = *(const bf16x8*)&As[(wr + i * 16 + l15) * GBK + rchunk * 8];
#pragma unroll
    for (int j = 0; j < 4; ++j)
      bf[j] = *(const bf16x8*)&Bs[(wc + j * 16 + l15) * GBK + rchunk * 8];
#pragma unroll
    for (int i = 0; i < 4; ++i)
#pragma unroll
      for (int j = 0; j < 4; ++j)
        acc[i][j] =
            __builtin_amdgcn_mfma_f32_16x16x32_bf16(af[i], bf[j], acc[i][j], 0, 0, 0);
  }

  // epilogue: C/D layout col=l&15, row=(l>>4)*4+reg
#pragma unroll
  for (int j = 0; j < 4; ++j) {
    int colr = col0 + wc + j * 16 + l15;
    float bv = bias[colr];
#pragma unroll
    for (int i = 0; i < 4; ++i) {
#pragma unroll
      for (int r = 0; r < 4; ++r) {
        int rowr = row0 + wr + i * 16 + lhi * 4 + r;
        float val = acc[i][j][r] + bv;
        if constexpr (BF16_OUT)
          ((bf16_t*)Cv)[(size_t)rowr * N + colr] = (bf16_t)val;
        else
          ((float*)Cv)[(size_t)rowr * N + colr] = val;
      }
    }
  }
}

// ---------------------------------------------------------------------------
// Transpose V out of qkv_bf into Vg[bh][d][t] (bf16).  (R12 form)
// ---------------------------------------------------------------------------
__global__ __launch_bounds__(256) void transpose_v(
    const bf16_t* __restrict__ qkv, bf16_t* __restrict__ Vg) {
  const int bh = blockIdx.y;
  const int b = bh >> 4, h = bh & 15;
  const int t0 = blockIdx.x * 64;
  const int tid = threadIdx.x;
  const int d = tid & 63;
  const int w = tid >> 6;
  alignas(16) bf16_t tmp[16];
#pragma unroll
  for (int j = 0; j < 16; ++j) {
    int t = t0 + w * 16 + j;
    tmp[j] = qkv[(size_t)(b * T_ + t) * D3_ + 2 * D_ + h * HD_ + d];
  }
  bf16_t* dst = Vg + (size_t)(bh * HD_ + d) * T_ + t0 + w * 16;
  *(uint4*)(dst) = *(const uint4*)(tmp);
  *(uint4*)(dst + 8) = *(const uint4*)(tmp + 8);
}

// ---------------------------------------------------------------------------
// Causal flash attention (R12 form, unchanged): swapped-QK^T 16x16x32 MFMA,
// 4 waves / QBLK=128, 2-barrier staged loop, fixed-max softmax (c=8).
// ---------------------------------------------------------------------------
#define QBLK 128
#define KBLK 64

__global__ __launch_bounds__(256, 4) void attn_fwd_mfma(
    const bf16_t* __restrict__ qkv, const bf16_t* __restrict__ Vg,
    bf16_t* __restrict__ y) {
  const int lin = blockIdx.x;
  const int bh = (lin & 7) * 8 + ((lin >> 3) & 7);  // XCD-local heads
  const int qt = (T_ / QBLK - 1) - (lin >> 6);      // tail-first
  const int b = bh >> 4, h = bh & 15;
  const int Q0 = qt * QBLK;
  const int tid = threadIdx.x;
  const int w = tid >> 6, l = tid & 63;
  const int l15 = l & 15, lhi = l >> 4;

  __shared__ __align__(16) bf16_t K_lds[2][KBLK * 64];
  __shared__ __align__(16) bf16_t V_lds[KBLK * 64];
  __shared__ __align__(16) bf16_t P_lds[4][16][72];

  const int sr = tid >> 3, sp = tid & 7;
  const int slc = sp ^ (sr & 7);
  const int swz = (l15 & 7);

  auto stageK = [&](int buf, int kt) {
    const bf16_t* src =
        qkv + (size_t)(b * T_ + kt * KBLK + sr) * D3_ + D_ + h * HD_ + slc * 8;
    char* dst = (char*)(&K_lds[buf][0]) + w * 1024;
    load_lds16(src, dst);
    load_lds16(src + (size_t)32 * D3_, dst + 4096);
  };
  auto stageV = [&](int kt) {
    const bf16_t* src = Vg + ((size_t)bh * HD_ + sr) * T_ + kt * KBLK + slc * 8;
    char* dst = (char*)(&V_lds[0]) + w * 1024;
    load_lds16(src, dst);
    load_lds16(src + (size_t)32 * T_, dst + 4096);
  };

  bf16x8 qf[2][2];
#pragma unroll
  for (int g = 0; g < 2; ++g) {
    int q = Q0 + w * 32 + g * 16 + l15;
#pragma unroll
    for (int c = 0; c < 2; ++c) {
      const bf16_t* p = qkv + (size_t)(b * T_ + q) * D3_ + h * HD_ + c * 32 + lhi * 8;
      bf16x8 v = *(const bf16x8*)p;
#pragma unroll
      for (int e = 0; e < 8; ++e) v[e] = (bf16_t)((float)v[e] * 0.125f);
      qf[g][c] = v;
    }
  }

  f32x4 accO[2][4];
#pragma unroll
  for (int g = 0; g < 2; ++g)
#pragma unroll
    for (int dg = 0; dg < 4; ++dg) accO[g][dg] = (f32x4){0.f, 0.f, 0.f, 0.f};
  float lsum[2] = {0.f, 0.f};
  const float FMAX = 8.f;

  const int ntiles = Q0 / KBLK + 2;
  const int qg0 = Q0 + w * 32;
  const int qg1 = qg0 + 16;

  stageK(0, 0);
  __syncthreads();

  for (int kt = 0; kt < ntiles; ++kt) {
    const int cur = kt & 1;
    const int ktb = kt * KBLK;
    stageV(kt);
    if (kt + 1 < ntiles) stageK(cur ^ 1, kt + 1);

    const bool act0 = (ktb <= qg0 + 15);
    const bool act1 = (ktb <= qg1 + 15);
    uint2 pp1[4];

#pragma unroll
    for (int g = 0; g < 2; ++g) {
      if (!(g == 0 ? act0 : act1)) continue;
      const int qg = g == 0 ? qg0 : qg1;

      f32x4 s[4];
#pragma unroll
      for (int n = 0; n < 4; ++n) s[n] = (f32x4){0.f, 0.f, 0.f, 0.f};
      __builtin_amdgcn_s_setprio(1);
#pragma unroll
      for (int c = 0; c < 2; ++c) {
#pragma unroll
        for (int n = 0; n < 4; ++n) {
          bf16x8 kf = *(const bf16x8*)&K_lds[cur][(n * 16 + l15) * 64 +
                                                 (((c * 4 + lhi) ^ swz) * 8)];
          s[n] = __builtin_amdgcn_mfma_f32_16x16x32_bf16(kf, qf[g][c], s[n], 0, 0, 0);
        }
      }
      __builtin_amdgcn_s_setprio(0);

      if (ktb + KBLK - 1 > qg) {
        const int qml = qg + l15 - ktb - lhi * 4;
#pragma unroll
        for (int n = 0; n < 4; ++n)
#pragma unroll
          for (int r = 0; r < 4; ++r)
            if (n * 16 + r > qml) s[n][r] = -INFINITY;
      }

      float rowsum = 0.f;
#pragma unroll
      for (int n = 0; n < 4; ++n) {
        alignas(8) bf16_t p4[4];
#pragma unroll
        for (int r = 0; r < 4; ++r) {
          float p = __expf(s[n][r] - FMAX);
          rowsum += p;
          p4[r] = (bf16_t)p;
        }
        if (g == 0)
          *(uint2*)&P_lds[w][l15][n * 16 + lhi * 4] = *(const uint2*)p4;
        else
          pp1[n] = *(const uint2*)p4;
      }
      lsum[g] += rowsum;
    }

    __syncthreads();

    if (act0) {
      __builtin_amdgcn_s_setprio(1);
#pragma unroll
      for (int c2 = 0; c2 < 2; ++c2) {
        bf16x8 pf = *(const bf16x8*)&P_lds[w][l15][c2 * 32 + lhi * 8];
#pragma unroll
        for (int dg = 0; dg < 4; ++dg) {
          bf16x8 vf = *(const bf16x8*)&V_lds[(dg * 16 + l15) * 64 +
                                             (((c2 * 4 + lhi) ^ swz) * 8)];
          accO[0][dg] =
              __builtin_amdgcn_mfma_f32_16x16x32_bf16(pf, vf, accO[0][dg], 0, 0, 0);
        }
      }
      __builtin_amdgcn_s_setprio(0);
    }
    if (act1) {
#pragma unroll
      for (int n = 0; n < 4; ++n)
        *(uint2*)&P_lds[w][l15][n * 16 + lhi * 4] = pp1[n];
      __builtin_amdgcn_s_setprio(1);
#pragma unroll
      for (int c2 = 0; c2 < 2; ++c2) {
        bf16x8 pf = *(const bf16x8*)&P_lds[w][l15][c2 * 32 + lhi * 8];
#pragma unroll
        for (int dg = 0; dg < 4; ++dg) {
          bf16x8 vf = *(const bf16x8*)&V_lds[(dg * 16 + l15) * 64 +
                                             (((c2 * 4 + lhi) ^ swz) * 8)];
          accO[1][dg] =
              __builtin_amdgcn_mfma_f32_16x16x32_bf16(pf, vf, accO[1][dg], 0, 0, 0);
        }
      }
      __builtin_amdgcn_s_setprio(0);
    }

    __syncthreads();
  }

#pragma unroll
  for (int g = 0; g < 2; ++g) {
    float ls = lsum[g];
    ls += __shfl_xor(ls, 16);
    ls += __shfl_xor(ls, 32);
#pragma unroll
    for (int r = 0; r < 4; ++r) {
      float lr = __shfl(ls, lhi * 4 + r);
      float inv = 1.f / lr;
      int q = Q0 + w * 32 + g * 16 + lhi * 4 + r;
      bf16_t* yr = y + (size_t)(b * T_ + q) * D_ + h * HD_ + l15;
#pragma unroll
      for (int dg = 0; dg < 4; ++dg) yr[dg * 16] = (bf16_t)(accO[g][dg][r] * inv);
    }
  }
}

// ---------------------------------------------------------------------------
extern "C" void kernel_launch(void* const* d_in, const int* in_sizes, int n_in,
                              void* d_out, int out_size, void* d_ws, size_t ws_size,
                              hipStream_t stream) {
  const float* x      = (const float*)d_in[0];
  const float* w_attn = (const float*)d_in[1];
  const float* b_attn = (const float*)d_in[2];
  const float* w_proj = (const float*)d_in[3];
  const float* b_proj = (const float*)d_in[4];
  float* out = (float*)d_out;

  const int M = B_ * T_;  // 8192

  bf16_t* xb      = (bf16_t*)d_ws;                         // 16 MB (reused as y_bf)
  bf16_t* wattnT  = xb + (size_t)M * D_;                   // 6 MB
  bf16_t* wprojT  = wattnT + (size_t)D3_ * D_;             // 2 MB
  bf16_t* qkv_bf  = wprojT + (size_t)D_ * D_;              // 48 MB
  bf16_t* Vg      = qkv_bf + (size_t)M * D3_;              // 16 MB
  bf16_t* y_bf    = xb;

  convert_bf16<<<2048, 256, 0, stream>>>(x, xb, M * D_ / 4);
  // both weight transposes in one launch
  transpose_convert2<<<dim3(D_ / 64, 64), 256, 0, stream>>>(
      w_attn, wattnT, w_proj, wprojT);
  // QKV GEMM (1536 blocks, XCD-swizzled)
  gemm_bt_mfma<true><<<(D3_ / GBN) * (M / GBM), 256, 0, stream>>>(
      xb, wattnT, b_attn, qkv_bf, M, D3_, D_);
  transpose_v<<<dim3(T_ / 64, B_ * H_), 256, 0, stream>>>(qkv_bf, Vg);
  attn_fwd_mfma<<<dim3(T_ / QBLK * B_ * H_), 256, 0, stream>>>(qkv_bf, Vg, y_bf);
  // proj GEMM (512 blocks, XCD-swizzled)
  gemm_bt_mfma<false><<<(D_ / GBN) * (M / GBM), 256, 0, stream>>>(
      y_bf, wprojT, b_proj, out, M, D_, D_);
}